// Round 10
// baseline (1144.530 us; speedup 1.0000x reference)
//
#include <hip/hip_runtime.h>
#include <hip/hip_bf16.h>

#define FDIM 512
#define HDIM 256
#define CDIM 64
#define KSTEPS 10

typedef __attribute__((ext_vector_type(8))) short bf16x8;
typedef __attribute__((ext_vector_type(4))) float f32x4;
typedef __attribute__((ext_vector_type(2))) float f32x2;

static __device__ __forceinline__ unsigned short f2bf(float f) {
  union { float f; unsigned int u; } x; x.f = f;
  unsigned int u = x.u;
  return (unsigned short)((u + 0x7fffu + ((u >> 16) & 1u)) >> 16);  // RNE
}
static __device__ __forceinline__ float bits2f(unsigned int u) {
  union { unsigned int u; float f; } x; x.u = u; return x.f;
}

// ---------------- weight prep: fp32 [K][N] -> bf16 transposed [N][K] -------
__global__ void prep_w(const float* __restrict__ W1, const float* __restrict__ W2,
                       unsigned short* __restrict__ W1t, unsigned short* __restrict__ W2t) {
  int i = blockIdx.x * 256 + threadIdx.x;
  if (i < FDIM * HDIM) { int k = i / HDIM, n = i % HDIM; W1t[(size_t)n * FDIM + k] = f2bf(W1[i]); }
  if (i < HDIM * CDIM) { int k = i / CDIM, n = i % CDIM; W2t[(size_t)n * HDIM + k] = f2bf(W2[i]); }
}

// ---------------- graph prep: XCD-partitioned by dst range -----------------
__global__ __launch_bounds__(256) void deg_x(const int* __restrict__ dst,
                                             int* __restrict__ deg, int E, float rinv) {
  const int rng = blockIdx.x & 7;
  const int g = (blockIdx.x >> 3) * 256 + threadIdx.x;
  const int stride = (gridDim.x >> 3) * 256;
  for (int i = g; i < E; i += stride) {
    const int d = dst[i];
    const int r = min(7, (int)((float)d * rinv));
    if (r == rng) atomicAdd(&deg[d], 1);
  }
}

__global__ void dinv_k(const int* __restrict__ deg, float* __restrict__ dinv, int n) {
  int i = blockIdx.x * 256 + threadIdx.x;
  if (i < n) dinv[i] = rsqrtf((float)deg[i] + 1.0f);  // +1 self-loop
}

__global__ void scan_block(const int* __restrict__ in, int* __restrict__ out,
                           int* __restrict__ bsum, int n) {
  __shared__ int tmp[1024];
  int i = blockIdx.x * 1024 + threadIdx.x;
  int v = (i < n) ? in[i] : 0;
  tmp[threadIdx.x] = v;
  __syncthreads();
  for (int off = 1; off < 1024; off <<= 1) {
    int t = (threadIdx.x >= off) ? tmp[threadIdx.x - off] : 0;
    __syncthreads();
    tmp[threadIdx.x] += t;
    __syncthreads();
  }
  if (i < n) out[i] = tmp[threadIdx.x] - v;  // exclusive
  if (threadIdx.x == 1023) bsum[blockIdx.x] = tmp[1023];
}

__global__ void scan_sums_par(const int* __restrict__ bsum, int* __restrict__ boff, int nb) {
  __shared__ int tmp[1024];
  int t = threadIdx.x;
  int v = (t < nb) ? bsum[t] : 0;
  tmp[t] = v;
  __syncthreads();
  for (int off = 1; off < 1024; off <<= 1) {
    int x = (t >= off) ? tmp[t - off] : 0;
    __syncthreads();
    tmp[t] += x;
    __syncthreads();
  }
  if (t < nb) boff[t] = tmp[t] - v;  // exclusive
}

__global__ void scan_add(int* __restrict__ rowptr, int* __restrict__ cursor,
                         const int* __restrict__ boff, int n, int total) {
  int i = blockIdx.x * 1024 + threadIdx.x;
  if (i < n) {
    int v = rowptr[i] + boff[blockIdx.x];
    rowptr[i] = v;
    cursor[i] = v;
  }
  if (i == 0) rowptr[n] = total;
}

// XCD-partitioned CSR fill: 8B record {src, bits(dinv[src])}
__global__ __launch_bounds__(256) void fill_x(const int* __restrict__ src,
                                              const int* __restrict__ dst,
                                              const float* __restrict__ dinv,
                                              int* __restrict__ cursor,
                                              uint2* __restrict__ edges, int E, float rinv) {
  const int rng = blockIdx.x & 7;
  const int g = (blockIdx.x >> 3) * 256 + threadIdx.x;
  const int stride = (gridDim.x >> 3) * 256;
  for (int i = g; i < E; i += stride) {
    const int d = dst[i];
    const int r = min(7, (int)((float)d * rinv));
    if (r == rng) {
      const int s = src[i];
      const int p = atomicAdd(&cursor[d], 1);
      union { float f; unsigned int u; } w; w.f = dinv[s];
      edges[p] = make_uint2((unsigned int)s, w.u);
    }
  }
}

// ---------------- GEMM1: h1 = relu(x @ W1 + b1), tile 64(M) x 256(N=all) ---
__global__ __launch_bounds__(256) void gemm1_k(const float* __restrict__ A,
                                               const unsigned short* __restrict__ Bt,
                                               const float* __restrict__ bias,
                                               unsigned short* __restrict__ C, int M) {
  __shared__ unsigned short Al[64][40];
  __shared__ unsigned short Bl[256][40];
  const int tid = threadIdx.x;
  const int wid = tid >> 6;
  const int lane = tid & 63;
  const int m0 = blockIdx.x * 64;
  const int srow = tid >> 2;
  const int scg = (tid & 3) * 8;
  f32x4 acc[16];
#pragma unroll
  for (int i = 0; i < 16; ++i) acc[i] = (f32x4){0.f, 0.f, 0.f, 0.f};
  for (int k0 = 0; k0 < FDIM; k0 += 32) {
    {
      const int gr = m0 + srow;
      unsigned short av[8];
      if (gr < M) {
        const float* p = A + (size_t)gr * FDIM + k0 + scg;
#pragma unroll
        for (int j = 0; j < 8; ++j) av[j] = f2bf(p[j]);
      } else {
#pragma unroll
        for (int j = 0; j < 8; ++j) av[j] = 0;
      }
      *(bf16x8*)(&Al[srow][scg]) = *(bf16x8*)av;
    }
#pragma unroll
    for (int j = 0; j < 4; ++j) {
      const int br = srow + 64 * j;
      bf16x8 v = *(const bf16x8*)(Bt + (size_t)br * FDIM + k0 + scg);
      *(bf16x8*)(&Bl[br][scg]) = v;
    }
    __syncthreads();
    bf16x8 a = *(const bf16x8*)(&Al[wid * 16 + (lane & 15)][(lane >> 4) * 8]);
#pragma unroll
    for (int nf = 0; nf < 16; ++nf) {
      bf16x8 b = *(const bf16x8*)(&Bl[nf * 16 + (lane & 15)][(lane >> 4) * 8]);
      acc[nf] = __builtin_amdgcn_mfma_f32_16x16x32_bf16(a, b, acc[nf], 0, 0, 0);
    }
    __syncthreads();
  }
#pragma unroll
  for (int nf = 0; nf < 16; ++nf) {
    const int colg = nf * 16 + (lane & 15);
    const float bb = bias[colg];
#pragma unroll
    for (int r = 0; r < 4; ++r) {
      const int rowg = m0 + wid * 16 + (lane >> 4) * 4 + r;
      if (rowg < M) {
        float v = fmaxf(acc[nf][r] + bb, 0.0f);
        C[(size_t)rowg * HDIM + colg] = f2bf(v);
      }
    }
  }
}

// ---------------- GEMM2: hb0 = h1 @ W2 + b2 -> bf16, tile 64x64 ------------
__global__ __launch_bounds__(256) void gemm2_k(const unsigned short* __restrict__ A,
                                               const unsigned short* __restrict__ Bt,
                                               const float* __restrict__ bias,
                                               unsigned short* __restrict__ C, int M) {
  __shared__ unsigned short Al[64][40];
  __shared__ unsigned short Bl[64][40];
  const int tid = threadIdx.x;
  const int wid = tid >> 6;
  const int lane = tid & 63;
  const int m0 = blockIdx.x * 64;
  const int srow = tid >> 2;
  const int scg = (tid & 3) * 8;
  f32x4 acc[4];
#pragma unroll
  for (int i = 0; i < 4; ++i) acc[i] = (f32x4){0.f, 0.f, 0.f, 0.f};
  for (int k0 = 0; k0 < HDIM; k0 += 32) {
    {
      const int gr = m0 + srow;
      if (gr < M) {
        bf16x8 v = *(const bf16x8*)(A + (size_t)gr * HDIM + k0 + scg);
        *(bf16x8*)(&Al[srow][scg]) = v;
      } else {
        bf16x8 z = {0, 0, 0, 0, 0, 0, 0, 0};
        *(bf16x8*)(&Al[srow][scg]) = z;
      }
    }
    {
      bf16x8 v = *(const bf16x8*)(Bt + (size_t)srow * HDIM + k0 + scg);
      *(bf16x8*)(&Bl[srow][scg]) = v;
    }
    __syncthreads();
    bf16x8 a = *(const bf16x8*)(&Al[wid * 16 + (lane & 15)][(lane >> 4) * 8]);
#pragma unroll
    for (int nf = 0; nf < 4; ++nf) {
      bf16x8 b = *(const bf16x8*)(&Bl[nf * 16 + (lane & 15)][(lane >> 4) * 8]);
      acc[nf] = __builtin_amdgcn_mfma_f32_16x16x32_bf16(a, b, acc[nf], 0, 0, 0);
    }
    __syncthreads();
  }
#pragma unroll
  for (int nf = 0; nf < 4; ++nf) {
    const int colg = nf * 16 + (lane & 15);
    const float bb = bias[colg];
#pragma unroll
    for (int r = 0; r < 4; ++r) {
      const int rowg = m0 + wid * 16 + (lane >> 4) * 4 + r;
      if (rowg < M) C[(size_t)rowg * CDIM + colg] = f2bf(acc[nf][r] + bb);
    }
  }
}

// ---------------- bf16 h0 -> fp8 e4m3 initial state ------------------------
__global__ __launch_bounds__(256) void cvt8_k(const unsigned short* __restrict__ hb0,
                                              unsigned char* __restrict__ g0, long total8) {
  long i = (long)blockIdx.x * 256 + threadIdx.x;   // one uint2 (8 ch) per thread
  if (i >= total8) return;
  const uint4 hv = *(const uint4*)(hb0 + i * 8);
  float o0 = bits2f(hv.x << 16), o1 = bits2f(hv.x & 0xffff0000u);
  float o2 = bits2f(hv.y << 16), o3 = bits2f(hv.y & 0xffff0000u);
  float o4 = bits2f(hv.z << 16), o5 = bits2f(hv.z & 0xffff0000u);
  float o6 = bits2f(hv.w << 16), o7 = bits2f(hv.w & 0xffff0000u);
  int lo = 0, hi = 0;
  lo = __builtin_amdgcn_cvt_pk_fp8_f32(o0, o1, lo, false);
  lo = __builtin_amdgcn_cvt_pk_fp8_f32(o2, o3, lo, true);
  hi = __builtin_amdgcn_cvt_pk_fp8_f32(o4, o5, hi, false);
  hi = __builtin_amdgcn_cvt_pk_fp8_f32(o6, o7, hi, true);
  *(uint2*)(g0 + i * 8) = make_uint2((unsigned int)lo, (unsigned int)hi);
}

// ---------------- APPNP step: fp8 state, 16 slots x 4 lanes, 16B gathers ---
// row = 64B = one line = 4 x dwordx4 -> 4 transactions per edge (was 8).
// lane = slot*4 + u; lane gathers 16 fp8 channels at byte offset u*16.
// out = 0.9*di*(Sum w_e h_e + di*h_r) + 0.1*h0_r
template <int LAST>
__global__ __launch_bounds__(256) void spmv8_k(const int* __restrict__ rowptr,
                                               const uint2* __restrict__ edges,
                                               const float* __restrict__ dinv,
                                               const unsigned char* __restrict__ hin,
                                               const unsigned short* __restrict__ hb0,
                                               void* __restrict__ hout, int n) {
  const int tid = threadIdx.x;
  const int wid = tid >> 6;
  const int lane = tid & 63;
  const int r = blockIdx.x * 4 + wid;
  if (r >= n) return;
  const int s = lane >> 2;      // slot 0..15
  const int u = lane & 3;       // channel 16-group: 16 fp8 = 16B at byte u*16
  const int e0 = rowptr[r], e1 = rowptr[r + 1];
  float a[16];
#pragma unroll
  for (int i = 0; i < 16; ++i) a[i] = 0.f;
  for (int e = e0; e < e1; e += 32) {
    unsigned long long rec[2];
#pragma unroll
    for (int j = 0; j < 2; ++j) {
      const int ee = e + s + 16 * j;
      rec[j] = (ee < e1)
                   ? __builtin_nontemporal_load((const unsigned long long*)(edges + ee))
                   : 0ull;   // src=0 (L1-hot line), w=0
    }
    uint4 hv[2];
#pragma unroll
    for (int j = 0; j < 2; ++j)
      hv[j] = *(const uint4*)(hin + (size_t)(unsigned int)rec[j] * 64 + u * 16);
#pragma unroll
    for (int j = 0; j < 2; ++j) {
      const float w = bits2f((unsigned int)(rec[j] >> 32));
      f32x2 p;
      p = __builtin_amdgcn_cvt_pk_f32_fp8((int)hv[j].x, false); a[0] += w * p.x;  a[1] += w * p.y;
      p = __builtin_amdgcn_cvt_pk_f32_fp8((int)hv[j].x, true);  a[2] += w * p.x;  a[3] += w * p.y;
      p = __builtin_amdgcn_cvt_pk_f32_fp8((int)hv[j].y, false); a[4] += w * p.x;  a[5] += w * p.y;
      p = __builtin_amdgcn_cvt_pk_f32_fp8((int)hv[j].y, true);  a[6] += w * p.x;  a[7] += w * p.y;
      p = __builtin_amdgcn_cvt_pk_f32_fp8((int)hv[j].z, false); a[8] += w * p.x;  a[9] += w * p.y;
      p = __builtin_amdgcn_cvt_pk_f32_fp8((int)hv[j].z, true);  a[10] += w * p.x; a[11] += w * p.y;
      p = __builtin_amdgcn_cvt_pk_f32_fp8((int)hv[j].w, false); a[12] += w * p.x; a[13] += w * p.y;
      p = __builtin_amdgcn_cvt_pk_f32_fp8((int)hv[j].w, true);  a[14] += w * p.x; a[15] += w * p.y;
    }
  }
  // reduce across the 16 slots (xor lane bits 2..5)
#pragma unroll
  for (int off = 4; off <= 32; off <<= 1) {
#pragma unroll
    for (int i = 0; i < 16; ++i) a[i] += __shfl_xor(a[i], off, 64);
  }
  if (s == 0) {  // lanes 0..3 finalize 16 channels each
    const float di = dinv[r];
    const uint4 hs = *(const uint4*)(hin + (size_t)r * 64 + u * 16);
    float sv[16];
    {
      f32x2 p;
      p = __builtin_amdgcn_cvt_pk_f32_fp8((int)hs.x, false); sv[0] = p.x;  sv[1] = p.y;
      p = __builtin_amdgcn_cvt_pk_f32_fp8((int)hs.x, true);  sv[2] = p.x;  sv[3] = p.y;
      p = __builtin_amdgcn_cvt_pk_f32_fp8((int)hs.y, false); sv[4] = p.x;  sv[5] = p.y;
      p = __builtin_amdgcn_cvt_pk_f32_fp8((int)hs.y, true);  sv[6] = p.x;  sv[7] = p.y;
      p = __builtin_amdgcn_cvt_pk_f32_fp8((int)hs.z, false); sv[8] = p.x;  sv[9] = p.y;
      p = __builtin_amdgcn_cvt_pk_f32_fp8((int)hs.z, true);  sv[10] = p.x; sv[11] = p.y;
      p = __builtin_amdgcn_cvt_pk_f32_fp8((int)hs.w, false); sv[12] = p.x; sv[13] = p.y;
      p = __builtin_amdgcn_cvt_pk_f32_fp8((int)hs.w, true);  sv[14] = p.x; sv[15] = p.y;
    }
    // teleport: bf16 h0, 32B (two uint4) per lane
    const uint4 hz0 = *(const uint4*)(hb0 + (size_t)r * 64 + u * 16);
    const uint4 hz1 = *(const uint4*)(hb0 + (size_t)r * 64 + u * 16 + 8);
    float tz[16];
    tz[0] = bits2f(hz0.x << 16); tz[1] = bits2f(hz0.x & 0xffff0000u);
    tz[2] = bits2f(hz0.y << 16); tz[3] = bits2f(hz0.y & 0xffff0000u);
    tz[4] = bits2f(hz0.z << 16); tz[5] = bits2f(hz0.z & 0xffff0000u);
    tz[6] = bits2f(hz0.w << 16); tz[7] = bits2f(hz0.w & 0xffff0000u);
    tz[8] = bits2f(hz1.x << 16); tz[9] = bits2f(hz1.x & 0xffff0000u);
    tz[10] = bits2f(hz1.y << 16); tz[11] = bits2f(hz1.y & 0xffff0000u);
    tz[12] = bits2f(hz1.z << 16); tz[13] = bits2f(hz1.z & 0xffff0000u);
    tz[14] = bits2f(hz1.w << 16); tz[15] = bits2f(hz1.w & 0xffff0000u);
    float o[16];
#pragma unroll
    for (int i = 0; i < 16; ++i)
      o[i] = 0.9f * di * (a[i] + di * sv[i]) + 0.1f * tz[i];
    if (LAST) {
      uint4 pk0, pk1;
      pk0.x = ((unsigned int)f2bf(o[1]) << 16) | f2bf(o[0]);
      pk0.y = ((unsigned int)f2bf(o[3]) << 16) | f2bf(o[2]);
      pk0.z = ((unsigned int)f2bf(o[5]) << 16) | f2bf(o[4]);
      pk0.w = ((unsigned int)f2bf(o[7]) << 16) | f2bf(o[6]);
      pk1.x = ((unsigned int)f2bf(o[9]) << 16) | f2bf(o[8]);
      pk1.y = ((unsigned int)f2bf(o[11]) << 16) | f2bf(o[10]);
      pk1.z = ((unsigned int)f2bf(o[13]) << 16) | f2bf(o[12]);
      pk1.w = ((unsigned int)f2bf(o[15]) << 16) | f2bf(o[14]);
      *(uint4*)((unsigned short*)hout + (size_t)r * 64 + u * 16) = pk0;
      *(uint4*)((unsigned short*)hout + (size_t)r * 64 + u * 16 + 8) = pk1;
    } else {
      int w0 = 0, w1 = 0, w2 = 0, w3 = 0;
      w0 = __builtin_amdgcn_cvt_pk_fp8_f32(o[0], o[1], w0, false);
      w0 = __builtin_amdgcn_cvt_pk_fp8_f32(o[2], o[3], w0, true);
      w1 = __builtin_amdgcn_cvt_pk_fp8_f32(o[4], o[5], w1, false);
      w1 = __builtin_amdgcn_cvt_pk_fp8_f32(o[6], o[7], w1, true);
      w2 = __builtin_amdgcn_cvt_pk_fp8_f32(o[8], o[9], w2, false);
      w2 = __builtin_amdgcn_cvt_pk_fp8_f32(o[10], o[11], w2, true);
      w3 = __builtin_amdgcn_cvt_pk_fp8_f32(o[12], o[13], w3, false);
      w3 = __builtin_amdgcn_cvt_pk_fp8_f32(o[14], o[15], w3, true);
      uint4 pk;
      pk.x = (unsigned int)w0; pk.y = (unsigned int)w1;
      pk.z = (unsigned int)w2; pk.w = (unsigned int)w3;
      *(uint4*)((unsigned char*)hout + (size_t)r * 64 + u * 16) = pk;
    }
  }
}

// ---------------- log_softmax over 64 classes (bf16 in, fp32 out) ----------
__global__ __launch_bounds__(256) void logsoftmax_k(const unsigned short* __restrict__ h,
                                                    float* __restrict__ out, int n) {
  const int r = blockIdx.x * 4 + (threadIdx.x >> 6);
  if (r >= n) return;
  const int lane = threadIdx.x & 63;
  float v = bits2f(((unsigned int)h[(size_t)r * 64 + lane]) << 16);
  float m = v;
#pragma unroll
  for (int o = 32; o; o >>= 1) m = fmaxf(m, __shfl_xor(m, o, 64));
  float ex = expf(v - m);
  float s = ex;
#pragma unroll
  for (int o = 32; o; o >>= 1) s += __shfl_xor(s, o, 64);
  out[(size_t)r * 64 + lane] = v - m - logf(s);
}

extern "C" void kernel_launch(void* const* d_in, const int* in_sizes, int n_in,
                              void* d_out, int out_size, void* d_ws, size_t ws_size,
                              hipStream_t stream) {
  const float* x = (const float*)d_in[0];
  const float* W1 = (const float*)d_in[1];
  const float* b1 = (const float*)d_in[2];
  const float* W2 = (const float*)d_in[3];
  const float* b2 = (const float*)d_in[4];
  const int* ei = (const int*)d_in[5];
  const int E = in_sizes[5] / 2;
  const int N = in_sizes[0] / FDIM;
  const int* src = ei;
  const int* dst = ei + E;
  const float rinv = 8.0f / (float)N;

  char* wp = (char*)d_ws;
  auto alloc = [&](size_t b) {
    char* p = wp;
    wp += (b + 255) & ~(size_t)255;
    return p;
  };
  unsigned short* W1t = (unsigned short*)alloc((size_t)HDIM * FDIM * 2);
  unsigned short* W2t = (unsigned short*)alloc((size_t)CDIM * HDIM * 2);
  unsigned short* h1 = (unsigned short*)alloc((size_t)N * HDIM * 2);
  unsigned short* hb0 = (unsigned short*)alloc((size_t)N * CDIM * 2);
  unsigned short* hF = (unsigned short*)alloc((size_t)N * CDIM * 2);
  unsigned char* g0 = (unsigned char*)alloc((size_t)N * CDIM);
  unsigned char* gA = (unsigned char*)alloc((size_t)N * CDIM);
  unsigned char* gB = (unsigned char*)alloc((size_t)N * CDIM);
  int* deg = (int*)alloc((size_t)N * 4);
  int* rowptr = (int*)alloc((size_t)(N + 1) * 4);
  int* cursor = (int*)alloc((size_t)N * 4);
  float* dinv = (float*)alloc((size_t)N * 4);
  int* bsum = (int*)alloc(4096);
  int* boff = (int*)alloc(4096);
  uint2* edges = (uint2*)alloc((size_t)E * 8);

  // weight prep
  prep_w<<<(FDIM * HDIM + 255) / 256, 256, 0, stream>>>(W1, W2, W1t, W2t);

  // graph prep: XCD-partitioned degree -> dinv -> scan -> XCD-partitioned fill
  hipMemsetAsync(deg, 0, (size_t)N * 4, stream);
  deg_x<<<2048, 256, 0, stream>>>(dst, deg, E, rinv);
  dinv_k<<<(N + 255) / 256, 256, 0, stream>>>(deg, dinv, N);
  const int nb = (N + 1023) >> 10;  // 98
  scan_block<<<nb, 1024, 0, stream>>>(deg, rowptr, bsum, N);
  scan_sums_par<<<1, 1024, 0, stream>>>(bsum, boff, nb);
  scan_add<<<nb, 1024, 0, stream>>>(rowptr, cursor, boff, N, E);
  fill_x<<<2048, 256, 0, stream>>>(src, dst, dinv, cursor, edges, E, rinv);

  // MLP
  gemm1_k<<<(N + 63) / 64, 256, 0, stream>>>(x, W1t, b1, h1, N);
  gemm2_k<<<(N + 63) / 64, 256, 0, stream>>>(h1, W2t, b2, hb0, N);
  const long total8 = (long)N * CDIM / 8;
  cvt8_k<<<(int)((total8 + 255) / 256), 256, 0, stream>>>(hb0, g0, total8);

  // APPNP propagation: fp8 state steps 0..8, final step writes bf16
  const unsigned char* cur = g0;
  unsigned char* bufs[2] = {gA, gB};
  for (int t = 0; t < KSTEPS - 1; ++t) {
    unsigned char* outb = bufs[t & 1];
    spmv8_k<0><<<(N + 3) / 4, 256, 0, stream>>>(rowptr, edges, dinv, cur, hb0, outb, N);
    cur = outb;
  }
  spmv8_k<1><<<(N + 3) / 4, 256, 0, stream>>>(rowptr, edges, dinv, cur, hb0, hF, N);

  // log_softmax -> d_out (fp32)
  logsoftmax_k<<<(N + 3) / 4, 256, 0, stream>>>(hF, (float*)d_out, N);
}

// Round 11
// 964.756 us; speedup vs baseline: 1.1863x; 1.1863x over previous
//
#include <hip/hip_runtime.h>
#include <hip/hip_bf16.h>

#define FDIM 512
#define HDIM 256
#define CDIM 64
#define KSTEPS 10

typedef __attribute__((ext_vector_type(8))) short bf16x8;
typedef __attribute__((ext_vector_type(4))) float f32x4;
typedef __attribute__((ext_vector_type(2))) float f32x2;

static __device__ __forceinline__ unsigned short f2bf(float f) {
  union { float f; unsigned int u; } x; x.f = f;
  unsigned int u = x.u;
  return (unsigned short)((u + 0x7fffu + ((u >> 16) & 1u)) >> 16);  // RNE
}
static __device__ __forceinline__ float bits2f(unsigned int u) {
  union { unsigned int u; float f; } x; x.u = u; return x.f;
}

// ---------------- weight prep: fp32 [K][N] -> bf16 transposed [N][K] -------
__global__ void prep_w(const float* __restrict__ W1, const float* __restrict__ W2,
                       unsigned short* __restrict__ W1t, unsigned short* __restrict__ W2t) {
  int i = blockIdx.x * 256 + threadIdx.x;
  if (i < FDIM * HDIM) { int k = i / HDIM, n = i % HDIM; W1t[(size_t)n * FDIM + k] = f2bf(W1[i]); }
  if (i < HDIM * CDIM) { int k = i / CDIM, n = i % CDIM; W2t[(size_t)n * HDIM + k] = f2bf(W2[i]); }
}

// ---------------- graph prep: XCD-partitioned by dst range -----------------
__global__ __launch_bounds__(256) void deg_x(const int* __restrict__ dst,
                                             int* __restrict__ deg, int E, float rinv) {
  const int rng = blockIdx.x & 7;
  const int g = (blockIdx.x >> 3) * 256 + threadIdx.x;
  const int stride = (gridDim.x >> 3) * 256;
  for (int i = g; i < E; i += stride) {
    const int d = dst[i];
    const int r = min(7, (int)((float)d * rinv));
    if (r == rng) atomicAdd(&deg[d], 1);
  }
}

__global__ void dinv_k(const int* __restrict__ deg, float* __restrict__ dinv, int n) {
  int i = blockIdx.x * 256 + threadIdx.x;
  if (i < n) dinv[i] = rsqrtf((float)deg[i] + 1.0f);  // +1 self-loop
}

__global__ void scan_block(const int* __restrict__ in, int* __restrict__ out,
                           int* __restrict__ bsum, int n) {
  __shared__ int tmp[1024];
  int i = blockIdx.x * 1024 + threadIdx.x;
  int v = (i < n) ? in[i] : 0;
  tmp[threadIdx.x] = v;
  __syncthreads();
  for (int off = 1; off < 1024; off <<= 1) {
    int t = (threadIdx.x >= off) ? tmp[threadIdx.x - off] : 0;
    __syncthreads();
    tmp[threadIdx.x] += t;
    __syncthreads();
  }
  if (i < n) out[i] = tmp[threadIdx.x] - v;  // exclusive
  if (threadIdx.x == 1023) bsum[blockIdx.x] = tmp[1023];
}

__global__ void scan_sums_par(const int* __restrict__ bsum, int* __restrict__ boff, int nb) {
  __shared__ int tmp[1024];
  int t = threadIdx.x;
  int v = (t < nb) ? bsum[t] : 0;
  tmp[t] = v;
  __syncthreads();
  for (int off = 1; off < 1024; off <<= 1) {
    int x = (t >= off) ? tmp[t - off] : 0;
    __syncthreads();
    tmp[t] += x;
    __syncthreads();
  }
  if (t < nb) boff[t] = tmp[t] - v;  // exclusive
}

__global__ void scan_add(int* __restrict__ rowptr, int* __restrict__ cursor,
                         const int* __restrict__ boff, int n, int total) {
  int i = blockIdx.x * 1024 + threadIdx.x;
  if (i < n) {
    int v = rowptr[i] + boff[blockIdx.x];
    rowptr[i] = v;
    cursor[i] = v;
  }
  if (i == 0) rowptr[n] = total;
}

// XCD-partitioned CSR fill: 8B record {src, bits(dinv[src])}
__global__ __launch_bounds__(256) void fill_x(const int* __restrict__ src,
                                              const int* __restrict__ dst,
                                              const float* __restrict__ dinv,
                                              int* __restrict__ cursor,
                                              uint2* __restrict__ edges, int E, float rinv) {
  const int rng = blockIdx.x & 7;
  const int g = (blockIdx.x >> 3) * 256 + threadIdx.x;
  const int stride = (gridDim.x >> 3) * 256;
  for (int i = g; i < E; i += stride) {
    const int d = dst[i];
    const int r = min(7, (int)((float)d * rinv));
    if (r == rng) {
      const int s = src[i];
      const int p = atomicAdd(&cursor[d], 1);
      union { float f; unsigned int u; } w; w.f = dinv[s];
      edges[p] = make_uint2((unsigned int)s, w.u);
    }
  }
}

// ---------------- GEMM1: h1 = relu(x @ W1 + b1), tile 64(M) x 256(N=all) ---
__global__ __launch_bounds__(256) void gemm1_k(const float* __restrict__ A,
                                               const unsigned short* __restrict__ Bt,
                                               const float* __restrict__ bias,
                                               unsigned short* __restrict__ C, int M) {
  __shared__ unsigned short Al[64][40];
  __shared__ unsigned short Bl[256][40];
  const int tid = threadIdx.x;
  const int wid = tid >> 6;
  const int lane = tid & 63;
  const int m0 = blockIdx.x * 64;
  const int srow = tid >> 2;
  const int scg = (tid & 3) * 8;
  f32x4 acc[16];
#pragma unroll
  for (int i = 0; i < 16; ++i) acc[i] = (f32x4){0.f, 0.f, 0.f, 0.f};
  for (int k0 = 0; k0 < FDIM; k0 += 32) {
    {
      const int gr = m0 + srow;
      unsigned short av[8];
      if (gr < M) {
        const float* p = A + (size_t)gr * FDIM + k0 + scg;
#pragma unroll
        for (int j = 0; j < 8; ++j) av[j] = f2bf(p[j]);
      } else {
#pragma unroll
        for (int j = 0; j < 8; ++j) av[j] = 0;
      }
      *(bf16x8*)(&Al[srow][scg]) = *(bf16x8*)av;
    }
#pragma unroll
    for (int j = 0; j < 4; ++j) {
      const int br = srow + 64 * j;
      bf16x8 v = *(const bf16x8*)(Bt + (size_t)br * FDIM + k0 + scg);
      *(bf16x8*)(&Bl[br][scg]) = v;
    }
    __syncthreads();
    bf16x8 a = *(const bf16x8*)(&Al[wid * 16 + (lane & 15)][(lane >> 4) * 8]);
#pragma unroll
    for (int nf = 0; nf < 16; ++nf) {
      bf16x8 b = *(const bf16x8*)(&Bl[nf * 16 + (lane & 15)][(lane >> 4) * 8]);
      acc[nf] = __builtin_amdgcn_mfma_f32_16x16x32_bf16(a, b, acc[nf], 0, 0, 0);
    }
    __syncthreads();
  }
#pragma unroll
  for (int nf = 0; nf < 16; ++nf) {
    const int colg = nf * 16 + (lane & 15);
    const float bb = bias[colg];
#pragma unroll
    for (int r = 0; r < 4; ++r) {
      const int rowg = m0 + wid * 16 + (lane >> 4) * 4 + r;
      if (rowg < M) {
        float v = fmaxf(acc[nf][r] + bb, 0.0f);
        C[(size_t)rowg * HDIM + colg] = f2bf(v);
      }
    }
  }
}

// ---------------- GEMM2: hb0 = h1 @ W2 + b2 -> bf16, tile 64x64 ------------
__global__ __launch_bounds__(256) void gemm2_k(const unsigned short* __restrict__ A,
                                               const unsigned short* __restrict__ Bt,
                                               const float* __restrict__ bias,
                                               unsigned short* __restrict__ C, int M) {
  __shared__ unsigned short Al[64][40];
  __shared__ unsigned short Bl[64][40];
  const int tid = threadIdx.x;
  const int wid = tid >> 6;
  const int lane = tid & 63;
  const int m0 = blockIdx.x * 64;
  const int srow = tid >> 2;
  const int scg = (tid & 3) * 8;
  f32x4 acc[4];
#pragma unroll
  for (int i = 0; i < 4; ++i) acc[i] = (f32x4){0.f, 0.f, 0.f, 0.f};
  for (int k0 = 0; k0 < HDIM; k0 += 32) {
    {
      const int gr = m0 + srow;
      if (gr < M) {
        bf16x8 v = *(const bf16x8*)(A + (size_t)gr * HDIM + k0 + scg);
        *(bf16x8*)(&Al[srow][scg]) = v;
      } else {
        bf16x8 z = {0, 0, 0, 0, 0, 0, 0, 0};
        *(bf16x8*)(&Al[srow][scg]) = z;
      }
    }
    {
      bf16x8 v = *(const bf16x8*)(Bt + (size_t)srow * HDIM + k0 + scg);
      *(bf16x8*)(&Bl[srow][scg]) = v;
    }
    __syncthreads();
    bf16x8 a = *(const bf16x8*)(&Al[wid * 16 + (lane & 15)][(lane >> 4) * 8]);
#pragma unroll
    for (int nf = 0; nf < 4; ++nf) {
      bf16x8 b = *(const bf16x8*)(&Bl[nf * 16 + (lane & 15)][(lane >> 4) * 8]);
      acc[nf] = __builtin_amdgcn_mfma_f32_16x16x32_bf16(a, b, acc[nf], 0, 0, 0);
    }
    __syncthreads();
  }
#pragma unroll
  for (int nf = 0; nf < 4; ++nf) {
    const int colg = nf * 16 + (lane & 15);
    const float bb = bias[colg];
#pragma unroll
    for (int r = 0; r < 4; ++r) {
      const int rowg = m0 + wid * 16 + (lane >> 4) * 4 + r;
      if (rowg < M) C[(size_t)rowg * CDIM + colg] = f2bf(acc[nf][r] + bb);
    }
  }
}

// ---------------- bf16 h0 -> fp8 e4m3 initial state ------------------------
__global__ __launch_bounds__(256) void cvt8_k(const unsigned short* __restrict__ hb0,
                                              unsigned char* __restrict__ g0, long total8) {
  long i = (long)blockIdx.x * 256 + threadIdx.x;   // one uint2 (8 ch) per thread
  if (i >= total8) return;
  const uint4 hv = *(const uint4*)(hb0 + i * 8);
  float o0 = bits2f(hv.x << 16), o1 = bits2f(hv.x & 0xffff0000u);
  float o2 = bits2f(hv.y << 16), o3 = bits2f(hv.y & 0xffff0000u);
  float o4 = bits2f(hv.z << 16), o5 = bits2f(hv.z & 0xffff0000u);
  float o6 = bits2f(hv.w << 16), o7 = bits2f(hv.w & 0xffff0000u);
  int lo = 0, hi = 0;
  lo = __builtin_amdgcn_cvt_pk_fp8_f32(o0, o1, lo, false);
  lo = __builtin_amdgcn_cvt_pk_fp8_f32(o2, o3, lo, true);
  hi = __builtin_amdgcn_cvt_pk_fp8_f32(o4, o5, hi, false);
  hi = __builtin_amdgcn_cvt_pk_fp8_f32(o6, o7, hi, true);
  *(uint2*)(g0 + i * 8) = make_uint2((unsigned int)lo, (unsigned int)hi);
}

// ---------------- APPNP step: fp8 state, TWO rows per wave -----------------
// Per row: 8 slots x 8 lanes x 8B (round-9 layout). Rows rA, rB=rA+1 share
// the wave; their record loads + gathers interleave -> 64 lines in flight
// per wave (2x round 9). CSR contiguity: e0B == e1A.
// out = 0.9*di*(Sum w_e h_e + di*h_r) + 0.1*h0_r
template <int LAST>
__global__ __launch_bounds__(256) void spmv8_k(const int* __restrict__ rowptr,
                                               const uint2* __restrict__ edges,
                                               const float* __restrict__ dinv,
                                               const unsigned char* __restrict__ hin,
                                               const unsigned short* __restrict__ hb0,
                                               void* __restrict__ hout, int n) {
  const int tid = threadIdx.x;
  const int wid = tid >> 6;
  const int lane = tid & 63;
  const int rA = blockIdx.x * 8 + wid * 2;
  if (rA >= n) return;
  const int rB = rA + 1;
  const bool hasB = (rB < n);
  const int s = lane >> 3;      // slot 0..7
  const int u = lane & 7;       // channel octet: 8 fp8 = 8B
  const int e0A = rowptr[rA];
  const int e1A = rowptr[rA + 1];
  const int e1B = hasB ? rowptr[rB + 1] : e1A;   // e0B == e1A
  float aA0 = 0.f, aA1 = 0.f, aA2 = 0.f, aA3 = 0.f;
  float aA4 = 0.f, aA5 = 0.f, aA6 = 0.f, aA7 = 0.f;
  float aB0 = 0.f, aB1 = 0.f, aB2 = 0.f, aB3 = 0.f;
  float aB4 = 0.f, aB5 = 0.f, aB6 = 0.f, aB7 = 0.f;
  int eA = e0A, eB = e1A;
  while (eA < e1A || eB < e1B) {
    unsigned long long recA[4], recB[4];
#pragma unroll
    for (int j = 0; j < 4; ++j) {
      const int ea = eA + s + 8 * j;
      recA[j] = (ea < e1A)
                    ? __builtin_nontemporal_load((const unsigned long long*)(edges + ea))
                    : 0ull;
      const int eb = eB + s + 8 * j;
      recB[j] = (eb < e1B)
                    ? __builtin_nontemporal_load((const unsigned long long*)(edges + eb))
                    : 0ull;
    }
    uint2 hvA[4], hvB[4];
#pragma unroll
    for (int j = 0; j < 4; ++j)
      hvA[j] = *(const uint2*)(hin + (size_t)(unsigned int)recA[j] * 64 + u * 8);
#pragma unroll
    for (int j = 0; j < 4; ++j)
      hvB[j] = *(const uint2*)(hin + (size_t)(unsigned int)recB[j] * 64 + u * 8);
#pragma unroll
    for (int j = 0; j < 4; ++j) {
      const float w = bits2f((unsigned int)(recA[j] >> 32));
      f32x2 p;
      p = __builtin_amdgcn_cvt_pk_f32_fp8((int)hvA[j].x, false); aA0 += w * p.x; aA1 += w * p.y;
      p = __builtin_amdgcn_cvt_pk_f32_fp8((int)hvA[j].x, true);  aA2 += w * p.x; aA3 += w * p.y;
      p = __builtin_amdgcn_cvt_pk_f32_fp8((int)hvA[j].y, false); aA4 += w * p.x; aA5 += w * p.y;
      p = __builtin_amdgcn_cvt_pk_f32_fp8((int)hvA[j].y, true);  aA6 += w * p.x; aA7 += w * p.y;
    }
#pragma unroll
    for (int j = 0; j < 4; ++j) {
      const float w = bits2f((unsigned int)(recB[j] >> 32));
      f32x2 p;
      p = __builtin_amdgcn_cvt_pk_f32_fp8((int)hvB[j].x, false); aB0 += w * p.x; aB1 += w * p.y;
      p = __builtin_amdgcn_cvt_pk_f32_fp8((int)hvB[j].x, true);  aB2 += w * p.x; aB3 += w * p.y;
      p = __builtin_amdgcn_cvt_pk_f32_fp8((int)hvB[j].y, false); aB4 += w * p.x; aB5 += w * p.y;
      p = __builtin_amdgcn_cvt_pk_f32_fp8((int)hvB[j].y, true);  aB6 += w * p.x; aB7 += w * p.y;
    }
    eA += 32; eB += 32;
  }
  // reduce across the 8 slots (xor lane bits 3..5)
#pragma unroll
  for (int off = 8; off <= 32; off <<= 1) {
    aA0 += __shfl_xor(aA0, off, 64); aA1 += __shfl_xor(aA1, off, 64);
    aA2 += __shfl_xor(aA2, off, 64); aA3 += __shfl_xor(aA3, off, 64);
    aA4 += __shfl_xor(aA4, off, 64); aA5 += __shfl_xor(aA5, off, 64);
    aA6 += __shfl_xor(aA6, off, 64); aA7 += __shfl_xor(aA7, off, 64);
    aB0 += __shfl_xor(aB0, off, 64); aB1 += __shfl_xor(aB1, off, 64);
    aB2 += __shfl_xor(aB2, off, 64); aB3 += __shfl_xor(aB3, off, 64);
    aB4 += __shfl_xor(aB4, off, 64); aB5 += __shfl_xor(aB5, off, 64);
    aB6 += __shfl_xor(aB6, off, 64); aB7 += __shfl_xor(aB7, off, 64);
  }
  // finalize: slot 0 -> row A, slot 1 -> row B; 8 lanes x 8 channels each
  if (s == 0 || (s == 1 && hasB)) {
    const int r = (s == 0) ? rA : rB;
    float a0 = (s == 0) ? aA0 : aB0, a1 = (s == 0) ? aA1 : aB1;
    float a2 = (s == 0) ? aA2 : aB2, a3 = (s == 0) ? aA3 : aB3;
    float a4 = (s == 0) ? aA4 : aB4, a5 = (s == 0) ? aA5 : aB5;
    float a6 = (s == 0) ? aA6 : aB6, a7 = (s == 0) ? aA7 : aB7;
    const float di = dinv[r];
    const uint2 hs = *(const uint2*)(hin + (size_t)r * 64 + u * 8);
    const uint4 hz = *(const uint4*)(hb0 + (size_t)r * 64 + u * 8);
    const f32x2 s0 = __builtin_amdgcn_cvt_pk_f32_fp8((int)hs.x, false);
    const f32x2 s1 = __builtin_amdgcn_cvt_pk_f32_fp8((int)hs.x, true);
    const f32x2 s2 = __builtin_amdgcn_cvt_pk_f32_fp8((int)hs.y, false);
    const f32x2 s3 = __builtin_amdgcn_cvt_pk_f32_fp8((int)hs.y, true);
    const float o0 = 0.9f * di * (a0 + di * s0.x) + 0.1f * bits2f(hz.x << 16);
    const float o1 = 0.9f * di * (a1 + di * s0.y) + 0.1f * bits2f(hz.x & 0xffff0000u);
    const float o2 = 0.9f * di * (a2 + di * s1.x) + 0.1f * bits2f(hz.y << 16);
    const float o3 = 0.9f * di * (a3 + di * s1.y) + 0.1f * bits2f(hz.y & 0xffff0000u);
    const float o4 = 0.9f * di * (a4 + di * s2.x) + 0.1f * bits2f(hz.z << 16);
    const float o5 = 0.9f * di * (a5 + di * s2.y) + 0.1f * bits2f(hz.z & 0xffff0000u);
    const float o6 = 0.9f * di * (a6 + di * s3.x) + 0.1f * bits2f(hz.w << 16);
    const float o7 = 0.9f * di * (a7 + di * s3.y) + 0.1f * bits2f(hz.w & 0xffff0000u);
    if (LAST) {
      uint4 pk;
      pk.x = ((unsigned int)f2bf(o1) << 16) | f2bf(o0);
      pk.y = ((unsigned int)f2bf(o3) << 16) | f2bf(o2);
      pk.z = ((unsigned int)f2bf(o5) << 16) | f2bf(o4);
      pk.w = ((unsigned int)f2bf(o7) << 16) | f2bf(o6);
      *(uint4*)((unsigned short*)hout + (size_t)r * 64 + u * 8) = pk;
    } else {
      int lo = 0, hi = 0;
      lo = __builtin_amdgcn_cvt_pk_fp8_f32(o0, o1, lo, false);
      lo = __builtin_amdgcn_cvt_pk_fp8_f32(o2, o3, lo, true);
      hi = __builtin_amdgcn_cvt_pk_fp8_f32(o4, o5, hi, false);
      hi = __builtin_amdgcn_cvt_pk_fp8_f32(o6, o7, hi, true);
      *(uint2*)((unsigned char*)hout + (size_t)r * 64 + u * 8) =
          make_uint2((unsigned int)lo, (unsigned int)hi);
    }
  }
}

// ---------------- log_softmax over 64 classes (bf16 in, fp32 out) ----------
__global__ __launch_bounds__(256) void logsoftmax_k(const unsigned short* __restrict__ h,
                                                    float* __restrict__ out, int n) {
  const int r = blockIdx.x * 4 + (threadIdx.x >> 6);
  if (r >= n) return;
  const int lane = threadIdx.x & 63;
  float v = bits2f(((unsigned int)h[(size_t)r * 64 + lane]) << 16);
  float m = v;
#pragma unroll
  for (int o = 32; o; o >>= 1) m = fmaxf(m, __shfl_xor(m, o, 64));
  float ex = expf(v - m);
  float s = ex;
#pragma unroll
  for (int o = 32; o; o >>= 1) s += __shfl_xor(s, o, 64);
  out[(size_t)r * 64 + lane] = v - m - logf(s);
}

extern "C" void kernel_launch(void* const* d_in, const int* in_sizes, int n_in,
                              void* d_out, int out_size, void* d_ws, size_t ws_size,
                              hipStream_t stream) {
  const float* x = (const float*)d_in[0];
  const float* W1 = (const float*)d_in[1];
  const float* b1 = (const float*)d_in[2];
  const float* W2 = (const float*)d_in[3];
  const float* b2 = (const float*)d_in[4];
  const int* ei = (const int*)d_in[5];
  const int E = in_sizes[5] / 2;
  const int N = in_sizes[0] / FDIM;
  const int* src = ei;
  const int* dst = ei + E;
  const float rinv = 8.0f / (float)N;

  char* wp = (char*)d_ws;
  auto alloc = [&](size_t b) {
    char* p = wp;
    wp += (b + 255) & ~(size_t)255;
    return p;
  };
  unsigned short* W1t = (unsigned short*)alloc((size_t)HDIM * FDIM * 2);
  unsigned short* W2t = (unsigned short*)alloc((size_t)CDIM * HDIM * 2);
  unsigned short* h1 = (unsigned short*)alloc((size_t)N * HDIM * 2);
  unsigned short* hb0 = (unsigned short*)alloc((size_t)N * CDIM * 2);
  unsigned short* hF = (unsigned short*)alloc((size_t)N * CDIM * 2);
  unsigned char* g0 = (unsigned char*)alloc((size_t)N * CDIM);
  unsigned char* gA = (unsigned char*)alloc((size_t)N * CDIM);
  unsigned char* gB = (unsigned char*)alloc((size_t)N * CDIM);
  int* deg = (int*)alloc((size_t)N * 4);
  int* rowptr = (int*)alloc((size_t)(N + 1) * 4);
  int* cursor = (int*)alloc((size_t)N * 4);
  float* dinv = (float*)alloc((size_t)N * 4);
  int* bsum = (int*)alloc(4096);
  int* boff = (int*)alloc(4096);
  uint2* edges = (uint2*)alloc((size_t)E * 8);

  // weight prep
  prep_w<<<(FDIM * HDIM + 255) / 256, 256, 0, stream>>>(W1, W2, W1t, W2t);

  // graph prep: XCD-partitioned degree -> dinv -> scan -> XCD-partitioned fill
  hipMemsetAsync(deg, 0, (size_t)N * 4, stream);
  deg_x<<<2048, 256, 0, stream>>>(dst, deg, E, rinv);
  dinv_k<<<(N + 255) / 256, 256, 0, stream>>>(deg, dinv, N);
  const int nb = (N + 1023) >> 10;  // 98
  scan_block<<<nb, 1024, 0, stream>>>(deg, rowptr, bsum, N);
  scan_sums_par<<<1, 1024, 0, stream>>>(bsum, boff, nb);
  scan_add<<<nb, 1024, 0, stream>>>(rowptr, cursor, boff, N, E);
  fill_x<<<2048, 256, 0, stream>>>(src, dst, dinv, cursor, edges, E, rinv);

  // MLP
  gemm1_k<<<(N + 63) / 64, 256, 0, stream>>>(x, W1t, b1, h1, N);
  gemm2_k<<<(N + 63) / 64, 256, 0, stream>>>(h1, W2t, b2, hb0, N);
  const long total8 = (long)N * CDIM / 8;
  cvt8_k<<<(int)((total8 + 255) / 256), 256, 0, stream>>>(hb0, g0, total8);

  // APPNP propagation: fp8 state steps 0..8, final step writes bf16
  const unsigned char* cur = g0;
  unsigned char* bufs[2] = {gA, gB};
  for (int t = 0; t < KSTEPS - 1; ++t) {
    unsigned char* outb = bufs[t & 1];
    spmv8_k<0><<<(N + 7) / 8, 256, 0, stream>>>(rowptr, edges, dinv, cur, hb0, outb, N);
    cur = outb;
  }
  spmv8_k<1><<<(N + 7) / 8, 256, 0, stream>>>(rowptr, edges, dinv, cur, hb0, hF, N);

  // log_softmax -> d_out (fp32)
  logsoftmax_k<<<(N + 7) / 8 * 2, 256, 0, stream>>>(hF, (float*)d_out, N);
}

// Round 12
// 946.398 us; speedup vs baseline: 1.2094x; 1.0194x over previous
//
#include <hip/hip_runtime.h>
#include <hip/hip_bf16.h>

#define FDIM 512
#define HDIM 256
#define CDIM 64
#define KSTEPS 10

typedef __attribute__((ext_vector_type(8))) short bf16x8;
typedef __attribute__((ext_vector_type(4))) float f32x4;
typedef __attribute__((ext_vector_type(2))) float f32x2;

static __device__ __forceinline__ unsigned short f2bf(float f) {
  union { float f; unsigned int u; } x; x.f = f;
  unsigned int u = x.u;
  return (unsigned short)((u + 0x7fffu + ((u >> 16) & 1u)) >> 16);  // RNE
}
static __device__ __forceinline__ float bits2f(unsigned int u) {
  union { unsigned int u; float f; } x; x.u = u; return x.f;
}

// ---------------- weight prep: fp32 [K][N] -> bf16 transposed [N][K] -------
__global__ void prep_w(const float* __restrict__ W1, const float* __restrict__ W2,
                       unsigned short* __restrict__ W1t, unsigned short* __restrict__ W2t) {
  int i = blockIdx.x * 256 + threadIdx.x;
  if (i < FDIM * HDIM) { int k = i / HDIM, n = i % HDIM; W1t[(size_t)n * FDIM + k] = f2bf(W1[i]); }
  if (i < HDIM * CDIM) { int k = i / CDIM, n = i % CDIM; W2t[(size_t)n * HDIM + k] = f2bf(W2[i]); }
}

// ---------------- graph prep: XCD-partitioned by dst range -----------------
__global__ __launch_bounds__(256) void deg_x(const int* __restrict__ dst,
                                             int* __restrict__ deg, int E, float rinv) {
  const int rng = blockIdx.x & 7;
  const int g = (blockIdx.x >> 3) * 256 + threadIdx.x;
  const int stride = (gridDim.x >> 3) * 256;
  for (int i = g; i < E; i += stride) {
    const int d = dst[i];
    const int r = min(7, (int)((float)d * rinv));
    if (r == rng) atomicAdd(&deg[d], 1);
  }
}

__global__ void dinv_k(const int* __restrict__ deg, float* __restrict__ dinv, int n) {
  int i = blockIdx.x * 256 + threadIdx.x;
  if (i < n) dinv[i] = rsqrtf((float)deg[i] + 1.0f);  // +1 self-loop
}

__global__ void scan_block(const int* __restrict__ in, int* __restrict__ out,
                           int* __restrict__ bsum, int n) {
  __shared__ int tmp[1024];
  int i = blockIdx.x * 1024 + threadIdx.x;
  int v = (i < n) ? in[i] : 0;
  tmp[threadIdx.x] = v;
  __syncthreads();
  for (int off = 1; off < 1024; off <<= 1) {
    int t = (threadIdx.x >= off) ? tmp[threadIdx.x - off] : 0;
    __syncthreads();
    tmp[threadIdx.x] += t;
    __syncthreads();
  }
  if (i < n) out[i] = tmp[threadIdx.x] - v;  // exclusive
  if (threadIdx.x == 1023) bsum[blockIdx.x] = tmp[1023];
}

__global__ void scan_sums_par(const int* __restrict__ bsum, int* __restrict__ boff, int nb) {
  __shared__ int tmp[1024];
  int t = threadIdx.x;
  int v = (t < nb) ? bsum[t] : 0;
  tmp[t] = v;
  __syncthreads();
  for (int off = 1; off < 1024; off <<= 1) {
    int x = (t >= off) ? tmp[t - off] : 0;
    __syncthreads();
    tmp[t] += x;
    __syncthreads();
  }
  if (t < nb) boff[t] = tmp[t] - v;  // exclusive
}

__global__ void scan_add(int* __restrict__ rowptr, int* __restrict__ cursor,
                         const int* __restrict__ boff, int n, int total) {
  int i = blockIdx.x * 1024 + threadIdx.x;
  if (i < n) {
    int v = rowptr[i] + boff[blockIdx.x];
    rowptr[i] = v;
    cursor[i] = v;
  }
  if (i == 0) rowptr[n] = total;
}

// XCD-partitioned CSR fill: 8B record {src, bits(dinv[src])}
__global__ __launch_bounds__(256) void fill_x(const int* __restrict__ src,
                                              const int* __restrict__ dst,
                                              const float* __restrict__ dinv,
                                              int* __restrict__ cursor,
                                              uint2* __restrict__ edges, int E, float rinv) {
  const int rng = blockIdx.x & 7;
  const int g = (blockIdx.x >> 3) * 256 + threadIdx.x;
  const int stride = (gridDim.x >> 3) * 256;
  for (int i = g; i < E; i += stride) {
    const int d = dst[i];
    const int r = min(7, (int)((float)d * rinv));
    if (r == rng) {
      const int s = src[i];
      const int p = atomicAdd(&cursor[d], 1);
      union { float f; unsigned int u; } w; w.f = dinv[s];
      edges[p] = make_uint2((unsigned int)s, w.u);
    }
  }
}

// ---------------- GEMM1: h1 = relu(x @ W1 + b1), tile 128(M) x 256(N=all) --
// 512 threads = 8 waves; wave w computes rows [16w,16w+16) x 256 cols.
// 8 waves share each staging barrier -> 2x MFMA work per staged element.
__global__ __launch_bounds__(512) void gemm1_k(const float* __restrict__ A,
                                               const unsigned short* __restrict__ Bt,
                                               const float* __restrict__ bias,
                                               unsigned short* __restrict__ C, int M) {
  __shared__ unsigned short Al[128][40];   // +8 pad
  __shared__ unsigned short Bl[256][40];
  const int tid = threadIdx.x;
  const int wid = tid >> 6;      // 0..7
  const int lane = tid & 63;
  const int m0 = blockIdx.x * 128;
  const int srow = tid >> 2;     // 0..127
  const int scg = (tid & 3) * 8; // 0,8,16,24
  f32x4 acc[16];
#pragma unroll
  for (int i = 0; i < 16; ++i) acc[i] = (f32x4){0.f, 0.f, 0.f, 0.f};
  for (int k0 = 0; k0 < FDIM; k0 += 32) {
    // stage A 128x32 fp32->bf16 (512 threads x 8 floats)
    {
      const int gr = m0 + srow;
      unsigned short av[8];
      if (gr < M) {
        const float* p = A + (size_t)gr * FDIM + k0 + scg;
#pragma unroll
        for (int j = 0; j < 8; ++j) av[j] = f2bf(p[j]);
      } else {
#pragma unroll
        for (int j = 0; j < 8; ++j) av[j] = 0;
      }
      *(bf16x8*)(&Al[srow][scg]) = *(bf16x8*)av;
    }
    // stage B 256x32 (512 threads x 2 rows)
#pragma unroll
    for (int j = 0; j < 2; ++j) {
      const int br = srow + 128 * j;
      bf16x8 v = *(const bf16x8*)(Bt + (size_t)br * FDIM + k0 + scg);
      *(bf16x8*)(&Bl[br][scg]) = v;
    }
    __syncthreads();
    bf16x8 a = *(const bf16x8*)(&Al[wid * 16 + (lane & 15)][(lane >> 4) * 8]);
#pragma unroll
    for (int nf = 0; nf < 16; ++nf) {
      bf16x8 b = *(const bf16x8*)(&Bl[nf * 16 + (lane & 15)][(lane >> 4) * 8]);
      acc[nf] = __builtin_amdgcn_mfma_f32_16x16x32_bf16(a, b, acc[nf], 0, 0, 0);
    }
    __syncthreads();
  }
#pragma unroll
  for (int nf = 0; nf < 16; ++nf) {
    const int colg = nf * 16 + (lane & 15);
    const float bb = bias[colg];
#pragma unroll
    for (int r = 0; r < 4; ++r) {
      const int rowg = m0 + wid * 16 + (lane >> 4) * 4 + r;
      if (rowg < M) {
        float v = fmaxf(acc[nf][r] + bb, 0.0f);
        C[(size_t)rowg * HDIM + colg] = f2bf(v);
      }
    }
  }
}

// ---------------- GEMM2: hb0 = h1 @ W2 + b2 -> bf16, tile 64x64 ------------
__global__ __launch_bounds__(256) void gemm2_k(const unsigned short* __restrict__ A,
                                               const unsigned short* __restrict__ Bt,
                                               const float* __restrict__ bias,
                                               unsigned short* __restrict__ C, int M) {
  __shared__ unsigned short Al[64][40];
  __shared__ unsigned short Bl[64][40];
  const int tid = threadIdx.x;
  const int wid = tid >> 6;
  const int lane = tid & 63;
  const int m0 = blockIdx.x * 64;
  const int srow = tid >> 2;
  const int scg = (tid & 3) * 8;
  f32x4 acc[4];
#pragma unroll
  for (int i = 0; i < 4; ++i) acc[i] = (f32x4){0.f, 0.f, 0.f, 0.f};
  for (int k0 = 0; k0 < HDIM; k0 += 32) {
    {
      const int gr = m0 + srow;
      if (gr < M) {
        bf16x8 v = *(const bf16x8*)(A + (size_t)gr * HDIM + k0 + scg);
        *(bf16x8*)(&Al[srow][scg]) = v;
      } else {
        bf16x8 z = {0, 0, 0, 0, 0, 0, 0, 0};
        *(bf16x8*)(&Al[srow][scg]) = z;
      }
    }
    {
      bf16x8 v = *(const bf16x8*)(Bt + (size_t)srow * HDIM + k0 + scg);
      *(bf16x8*)(&Bl[srow][scg]) = v;
    }
    __syncthreads();
    bf16x8 a = *(const bf16x8*)(&Al[wid * 16 + (lane & 15)][(lane >> 4) * 8]);
#pragma unroll
    for (int nf = 0; nf < 4; ++nf) {
      bf16x8 b = *(const bf16x8*)(&Bl[nf * 16 + (lane & 15)][(lane >> 4) * 8]);
      acc[nf] = __builtin_amdgcn_mfma_f32_16x16x32_bf16(a, b, acc[nf], 0, 0, 0);
    }
    __syncthreads();
  }
#pragma unroll
  for (int nf = 0; nf < 4; ++nf) {
    const int colg = nf * 16 + (lane & 15);
    const float bb = bias[colg];
#pragma unroll
    for (int r = 0; r < 4; ++r) {
      const int rowg = m0 + wid * 16 + (lane >> 4) * 4 + r;
      if (rowg < M) C[(size_t)rowg * CDIM + colg] = f2bf(acc[nf][r] + bb);
    }
  }
}

// ---------------- bf16 h0 -> fp8 e4m3 initial state ------------------------
__global__ __launch_bounds__(256) void cvt8_k(const unsigned short* __restrict__ hb0,
                                              unsigned char* __restrict__ g0, long total8) {
  long i = (long)blockIdx.x * 256 + threadIdx.x;   // one uint2 (8 ch) per thread
  if (i >= total8) return;
  const uint4 hv = *(const uint4*)(hb0 + i * 8);
  float o0 = bits2f(hv.x << 16), o1 = bits2f(hv.x & 0xffff0000u);
  float o2 = bits2f(hv.y << 16), o3 = bits2f(hv.y & 0xffff0000u);
  float o4 = bits2f(hv.z << 16), o5 = bits2f(hv.z & 0xffff0000u);
  float o6 = bits2f(hv.w << 16), o7 = bits2f(hv.w & 0xffff0000u);
  int lo = 0, hi = 0;
  lo = __builtin_amdgcn_cvt_pk_fp8_f32(o0, o1, lo, false);
  lo = __builtin_amdgcn_cvt_pk_fp8_f32(o2, o3, lo, true);
  hi = __builtin_amdgcn_cvt_pk_fp8_f32(o4, o5, hi, false);
  hi = __builtin_amdgcn_cvt_pk_fp8_f32(o6, o7, hi, true);
  *(uint2*)(g0 + i * 8) = make_uint2((unsigned int)lo, (unsigned int)hi);
}

// ---------------- APPNP step: fp8 state, TWO rows per wave -----------------
// Per row: 8 slots x 8 lanes x 8B. Rows rA, rB=rA+1 interleave their record
// loads + gathers -> 64 lines in flight per wave. At the measured L3
// random-request ceiling (~50 G-req/s).
template <int LAST>
__global__ __launch_bounds__(256) void spmv8_k(const int* __restrict__ rowptr,
                                               const uint2* __restrict__ edges,
                                               const float* __restrict__ dinv,
                                               const unsigned char* __restrict__ hin,
                                               const unsigned short* __restrict__ hb0,
                                               void* __restrict__ hout, int n) {
  const int tid = threadIdx.x;
  const int wid = tid >> 6;
  const int lane = tid & 63;
  const int rA = blockIdx.x * 8 + wid * 2;
  if (rA >= n) return;
  const int rB = rA + 1;
  const bool hasB = (rB < n);
  const int s = lane >> 3;      // slot 0..7
  const int u = lane & 7;       // channel octet: 8 fp8 = 8B
  const int e0A = rowptr[rA];
  const int e1A = rowptr[rA + 1];
  const int e1B = hasB ? rowptr[rB + 1] : e1A;   // e0B == e1A
  float aA0 = 0.f, aA1 = 0.f, aA2 = 0.f, aA3 = 0.f;
  float aA4 = 0.f, aA5 = 0.f, aA6 = 0.f, aA7 = 0.f;
  float aB0 = 0.f, aB1 = 0.f, aB2 = 0.f, aB3 = 0.f;
  float aB4 = 0.f, aB5 = 0.f, aB6 = 0.f, aB7 = 0.f;
  int eA = e0A, eB = e1A;
  while (eA < e1A || eB < e1B) {
    unsigned long long recA[4], recB[4];
#pragma unroll
    for (int j = 0; j < 4; ++j) {
      const int ea = eA + s + 8 * j;
      recA[j] = (ea < e1A)
                    ? __builtin_nontemporal_load((const unsigned long long*)(edges + ea))
                    : 0ull;
      const int eb = eB + s + 8 * j;
      recB[j] = (eb < e1B)
                    ? __builtin_nontemporal_load((const unsigned long long*)(edges + eb))
                    : 0ull;
    }
    uint2 hvA[4], hvB[4];
#pragma unroll
    for (int j = 0; j < 4; ++j)
      hvA[j] = *(const uint2*)(hin + (size_t)(unsigned int)recA[j] * 64 + u * 8);
#pragma unroll
    for (int j = 0; j < 4; ++j)
      hvB[j] = *(const uint2*)(hin + (size_t)(unsigned int)recB[j] * 64 + u * 8);
#pragma unroll
    for (int j = 0; j < 4; ++j) {
      const float w = bits2f((unsigned int)(recA[j] >> 32));
      f32x2 p;
      p = __builtin_amdgcn_cvt_pk_f32_fp8((int)hvA[j].x, false); aA0 += w * p.x; aA1 += w * p.y;
      p = __builtin_amdgcn_cvt_pk_f32_fp8((int)hvA[j].x, true);  aA2 += w * p.x; aA3 += w * p.y;
      p = __builtin_amdgcn_cvt_pk_f32_fp8((int)hvA[j].y, false); aA4 += w * p.x; aA5 += w * p.y;
      p = __builtin_amdgcn_cvt_pk_f32_fp8((int)hvA[j].y, true);  aA6 += w * p.x; aA7 += w * p.y;
    }
#pragma unroll
    for (int j = 0; j < 4; ++j) {
      const float w = bits2f((unsigned int)(recB[j] >> 32));
      f32x2 p;
      p = __builtin_amdgcn_cvt_pk_f32_fp8((int)hvB[j].x, false); aB0 += w * p.x; aB1 += w * p.y;
      p = __builtin_amdgcn_cvt_pk_f32_fp8((int)hvB[j].x, true);  aB2 += w * p.x; aB3 += w * p.y;
      p = __builtin_amdgcn_cvt_pk_f32_fp8((int)hvB[j].y, false); aB4 += w * p.x; aB5 += w * p.y;
      p = __builtin_amdgcn_cvt_pk_f32_fp8((int)hvB[j].y, true);  aB6 += w * p.x; aB7 += w * p.y;
    }
    eA += 32; eB += 32;
  }
#pragma unroll
  for (int off = 8; off <= 32; off <<= 1) {
    aA0 += __shfl_xor(aA0, off, 64); aA1 += __shfl_xor(aA1, off, 64);
    aA2 += __shfl_xor(aA2, off, 64); aA3 += __shfl_xor(aA3, off, 64);
    aA4 += __shfl_xor(aA4, off, 64); aA5 += __shfl_xor(aA5, off, 64);
    aA6 += __shfl_xor(aA6, off, 64); aA7 += __shfl_xor(aA7, off, 64);
    aB0 += __shfl_xor(aB0, off, 64); aB1 += __shfl_xor(aB1, off, 64);
    aB2 += __shfl_xor(aB2, off, 64); aB3 += __shfl_xor(aB3, off, 64);
    aB4 += __shfl_xor(aB4, off, 64); aB5 += __shfl_xor(aB5, off, 64);
    aB6 += __shfl_xor(aB6, off, 64); aB7 += __shfl_xor(aB7, off, 64);
  }
  if (s == 0 || (s == 1 && hasB)) {
    const int r = (s == 0) ? rA : rB;
    float a0 = (s == 0) ? aA0 : aB0, a1 = (s == 0) ? aA1 : aB1;
    float a2 = (s == 0) ? aA2 : aB2, a3 = (s == 0) ? aA3 : aB3;
    float a4 = (s == 0) ? aA4 : aB4, a5 = (s == 0) ? aA5 : aB5;
    float a6 = (s == 0) ? aA6 : aB6, a7 = (s == 0) ? aA7 : aB7;
    const float di = dinv[r];
    const uint2 hs = *(const uint2*)(hin + (size_t)r * 64 + u * 8);
    const uint4 hz = *(const uint4*)(hb0 + (size_t)r * 64 + u * 8);
    const f32x2 s0 = __builtin_amdgcn_cvt_pk_f32_fp8((int)hs.x, false);
    const f32x2 s1 = __builtin_amdgcn_cvt_pk_f32_fp8((int)hs.x, true);
    const f32x2 s2 = __builtin_amdgcn_cvt_pk_f32_fp8((int)hs.y, false);
    const f32x2 s3 = __builtin_amdgcn_cvt_pk_f32_fp8((int)hs.y, true);
    const float o0 = 0.9f * di * (a0 + di * s0.x) + 0.1f * bits2f(hz.x << 16);
    const float o1 = 0.9f * di * (a1 + di * s0.y) + 0.1f * bits2f(hz.x & 0xffff0000u);
    const float o2 = 0.9f * di * (a2 + di * s1.x) + 0.1f * bits2f(hz.y << 16);
    const float o3 = 0.9f * di * (a3 + di * s1.y) + 0.1f * bits2f(hz.y & 0xffff0000u);
    const float o4 = 0.9f * di * (a4 + di * s2.x) + 0.1f * bits2f(hz.z << 16);
    const float o5 = 0.9f * di * (a5 + di * s2.y) + 0.1f * bits2f(hz.z & 0xffff0000u);
    const float o6 = 0.9f * di * (a6 + di * s3.x) + 0.1f * bits2f(hz.w << 16);
    const float o7 = 0.9f * di * (a7 + di * s3.y) + 0.1f * bits2f(hz.w & 0xffff0000u);
    if (LAST) {
      uint4 pk;
      pk.x = ((unsigned int)f2bf(o1) << 16) | f2bf(o0);
      pk.y = ((unsigned int)f2bf(o3) << 16) | f2bf(o2);
      pk.z = ((unsigned int)f2bf(o5) << 16) | f2bf(o4);
      pk.w = ((unsigned int)f2bf(o7) << 16) | f2bf(o6);
      *(uint4*)((unsigned short*)hout + (size_t)r * 64 + u * 8) = pk;
    } else {
      int lo = 0, hi = 0;
      lo = __builtin_amdgcn_cvt_pk_fp8_f32(o0, o1, lo, false);
      lo = __builtin_amdgcn_cvt_pk_fp8_f32(o2, o3, lo, true);
      hi = __builtin_amdgcn_cvt_pk_fp8_f32(o4, o5, hi, false);
      hi = __builtin_amdgcn_cvt_pk_fp8_f32(o6, o7, hi, true);
      *(uint2*)((unsigned char*)hout + (size_t)r * 64 + u * 8) =
          make_uint2((unsigned int)lo, (unsigned int)hi);
    }
  }
}

// ---------------- log_softmax over 64 classes (bf16 in, fp32 out) ----------
__global__ __launch_bounds__(256) void logsoftmax_k(const unsigned short* __restrict__ h,
                                                    float* __restrict__ out, int n) {
  const int r = blockIdx.x * 4 + (threadIdx.x >> 6);
  if (r >= n) return;
  const int lane = threadIdx.x & 63;
  float v = bits2f(((unsigned int)h[(size_t)r * 64 + lane]) << 16);
  float m = v;
#pragma unroll
  for (int o = 32; o; o >>= 1) m = fmaxf(m, __shfl_xor(m, o, 64));
  float ex = expf(v - m);
  float s = ex;
#pragma unroll
  for (int o = 32; o; o >>= 1) s += __shfl_xor(s, o, 64);
  out[(size_t)r * 64 + lane] = v - m - logf(s);
}

extern "C" void kernel_launch(void* const* d_in, const int* in_sizes, int n_in,
                              void* d_out, int out_size, void* d_ws, size_t ws_size,
                              hipStream_t stream) {
  const float* x = (const float*)d_in[0];
  const float* W1 = (const float*)d_in[1];
  const float* b1 = (const float*)d_in[2];
  const float* W2 = (const float*)d_in[3];
  const float* b2 = (const float*)d_in[4];
  const int* ei = (const int*)d_in[5];
  const int E = in_sizes[5] / 2;
  const int N = in_sizes[0] / FDIM;
  const int* src = ei;
  const int* dst = ei + E;
  const float rinv = 8.0f / (float)N;

  char* wp = (char*)d_ws;
  auto alloc = [&](size_t b) {
    char* p = wp;
    wp += (b + 255) & ~(size_t)255;
    return p;
  };
  unsigned short* W1t = (unsigned short*)alloc((size_t)HDIM * FDIM * 2);
  unsigned short* W2t = (unsigned short*)alloc((size_t)CDIM * HDIM * 2);
  unsigned short* h1 = (unsigned short*)alloc((size_t)N * HDIM * 2);
  unsigned short* hb0 = (unsigned short*)alloc((size_t)N * CDIM * 2);
  unsigned short* hF = (unsigned short*)alloc((size_t)N * CDIM * 2);
  unsigned char* g0 = (unsigned char*)alloc((size_t)N * CDIM);
  unsigned char* gA = (unsigned char*)alloc((size_t)N * CDIM);
  unsigned char* gB = (unsigned char*)alloc((size_t)N * CDIM);
  int* deg = (int*)alloc((size_t)N * 4);
  int* rowptr = (int*)alloc((size_t)(N + 1) * 4);
  int* cursor = (int*)alloc((size_t)N * 4);
  float* dinv = (float*)alloc((size_t)N * 4);
  int* bsum = (int*)alloc(4096);
  int* boff = (int*)alloc(4096);
  uint2* edges = (uint2*)alloc((size_t)E * 8);

  // weight prep
  prep_w<<<(FDIM * HDIM + 255) / 256, 256, 0, stream>>>(W1, W2, W1t, W2t);

  // graph prep: XCD-partitioned degree -> dinv -> scan -> XCD-partitioned fill
  hipMemsetAsync(deg, 0, (size_t)N * 4, stream);
  deg_x<<<2048, 256, 0, stream>>>(dst, deg, E, rinv);
  dinv_k<<<(N + 255) / 256, 256, 0, stream>>>(deg, dinv, N);
  const int nb = (N + 1023) >> 10;  // 98
  scan_block<<<nb, 1024, 0, stream>>>(deg, rowptr, bsum, N);
  scan_sums_par<<<1, 1024, 0, stream>>>(bsum, boff, nb);
  scan_add<<<nb, 1024, 0, stream>>>(rowptr, cursor, boff, N, E);
  fill_x<<<2048, 256, 0, stream>>>(src, dst, dinv, cursor, edges, E, rinv);

  // MLP
  gemm1_k<<<(N + 127) / 128, 512, 0, stream>>>(x, W1t, b1, h1, N);
  gemm2_k<<<(N + 63) / 64, 256, 0, stream>>>(h1, W2t, b2, hb0, N);
  const long total8 = (long)N * CDIM / 8;
  cvt8_k<<<(int)((total8 + 255) / 256), 256, 0, stream>>>(hb0, g0, total8);

  // APPNP propagation: fp8 state steps 0..8, final step writes bf16
  const unsigned char* cur = g0;
  unsigned char* bufs[2] = {gA, gB};
  for (int t = 0; t < KSTEPS - 1; ++t) {
    unsigned char* outb = bufs[t & 1];
    spmv8_k<0><<<(N + 7) / 8, 256, 0, stream>>>(rowptr, edges, dinv, cur, hb0, outb, N);
    cur = outb;
  }
  spmv8_k<1><<<(N + 7) / 8, 256, 0, stream>>>(rowptr, edges, dinv, cur, hb0, hF, N);

  // log_softmax -> d_out (fp32)
  logsoftmax_k<<<(N + 3) / 4, 256, 0, stream>>>(hF, (float*)d_out, N);
}